// Round 3
// baseline (798.830 us; speedup 1.0000x reference)
//
#include <hip/hip_runtime.h>
#include <math.h>

#define NCAP 10
#define IC   6912
#define NJG  1152                 // j-groups (6 j each) -> 3x more waves in flight
#define NSLOT (NJG * 2)           // part slots (2304 = 8 * 288, XCD-swizzlable)
#define WPAIRS ((IC * NCAP) / 2)  // 34560 W tile-pairs

typedef __attribute__((ext_vector_type(4))) float f32x4;
typedef __attribute__((ext_vector_type(8))) short bf16x8;

// fp32 -> bf16 RNE
static __device__ inline unsigned short f2bf(float f) {
    unsigned int u = __float_as_uint(f);
    unsigned int r = u + 0x7FFFu + ((u >> 16) & 1u);
    return (unsigned short)(r >> 16);
}

// Prep: blocks <1024 transpose W into MFMA A-fragment order (R5-proven body);
// blocks >=1024 (one per j) convert x into B-fragment order bf16.
__global__ __launch_bounds__(256) void prep_kernel(
    const float* __restrict__ x, const float* __restrict__ W,
    unsigned short* __restrict__ w_t, unsigned short* __restrict__ x_t,
    int use_xt)
{
    __shared__ float lds[4 * 1312];
    const int tid  = threadIdx.x;
    const int lane = tid & 63;
    const int wv   = tid >> 6;

    if (blockIdx.x < 1024) {
        float* L0 = lds + wv * 1312;
        const int gw = blockIdx.x * 4 + wv;
        const int lr  = lane & 31;
        const int reg = lane >> 5;
        const int ia  = lr >> 2, oq = lr & 3;
        const int o   = lr & 15, kq2 = lr >> 4;
        const float4* W4 = (const float4*)W;
        int itc = 0;
        for (int p = gw; p < WPAIRS; p += 4096, ++itc) {
            float* L = L0 + (itc & 1) * 656;
            const int tl = p * 2 + reg;          // tile id = j*10 + n
            const int n = tl % 10, j = tl / 10;
            const float4* src = W4 + ((size_t)n * IC + j) * 64;
            float4 a = src[lr];
            float4 c = src[lr + 32];
            *(float4*)&L[reg * 328 + ia * 20 + oq * 4] = a;
            *(float4*)&L[reg * 328 + (ia + 8) * 20 + oq * 4] = c;
            bf16x8 fr;
            #pragma unroll
            for (int t = 0; t < 8; ++t)
                fr[t] = (short)f2bf(L[reg * 328 + (kq2 * 8 + t) * 20 + o]);
            *(bf16x8*)&w_t[(size_t)tl * 256 + lr * 8] = fr;
        }
    } else if (use_xt) {
        const int j  = blockIdx.x - 1024;        // 0..6911
        const int bg = wv;                       // b-group of 16
        if (lane < 32) {
            const int bl = lane & 15, kq = lane >> 4;
            const float* xp = x + ((size_t)(bg * 16 + bl) * IC + j) * 16 + kq * 8;
            float4 x0 = *(const float4*)xp;
            float4 x1 = *(const float4*)(xp + 4);
            bf16x8 fr;
            fr[0] = (short)f2bf(x0.x); fr[1] = (short)f2bf(x0.y);
            fr[2] = (short)f2bf(x0.z); fr[3] = (short)f2bf(x0.w);
            fr[4] = (short)f2bf(x1.x); fr[5] = (short)f2bf(x1.y);
            fr[6] = (short)f2bf(x1.z); fr[7] = (short)f2bf(x1.w);
            *(bf16x8*)&x_t[((size_t)j * 4 + bg) * 256 + lane * 8] = fr;
        }
    }
}

// Routing sweep, two-pass MFMA + explicit double buffer, vv in LDS.
// Block 256 = 4 waves = bg_l(2) x jw(2); covers 32 b's (bh half), 6 j's
// (3 per jw-wave). R0/R2-proven body; only the j-tiling is finer so the
// grid (2304 blocks) raises residency to ~24 waves/CU (was grid-capped 12).
// Bijective XCD swizzle keeps the bh=0/1 pair of each jg on one XCD L2.
// Layouts (R2/R5-proven): A[m=o=lane&15][k=(lane>>4)*8+t], B[k][b=lane&15],
// D col=lane&15(=b) row=(lane>>4)*4+reg(=o); K 16->32 zero-padded via zero
// fragments on lanes>=32 (outputs on ALL lanes are valid).
__global__ __launch_bounds__(256, 6) void sweep_kernel(
    const float* __restrict__ x, const unsigned short* __restrict__ x_t,
    const unsigned short* __restrict__ w_t, const float* __restrict__ vsum,
    float* __restrict__ part, int iter, int use_xt)
{
    __shared__ float smem[32 * 164];      // vv tile during loop; cbuf at end

    const int tid  = threadIdx.x;
    const int lane = tid & 63;
    const int wave = tid >> 6;
    const int bl   = lane & 15;
    const int kq   = lane >> 4;
    const bool act = (lane < 32);
    // XCD swizzle: logical slot; pairs (2k,2k+1) come from blockIdx b,b+8.
    const int logical = ((int)blockIdx.x & 7) * (NSLOT / 8) + ((int)blockIdx.x >> 3);
    const int bh   = logical & 1;
    const int jg   = logical >> 1;
    const int bg_l = wave & 1;
    const int jw   = wave >> 1;
    const int b    = bh * 32 + bg_l * 16 + bl;
    const int j0   = jg * 6 + jw * 3;
    const int vrow = (bg_l * 16 + bl) * 164;

    const f32x4 zf = (f32x4){0.f, 0.f, 0.f, 0.f};
    const bf16x8 zb = (bf16x8){0, 0, 0, 0, 0, 0, 0, 0};

    if (iter > 0) {
        // vectorized vsum -> LDS (float4, 5 per thread)
        const float4* vs4 = (const float4*)(vsum + bh * 5120);
        for (int i = tid; i < 1280; i += 256) {
            const int row = i / 40, col = (i % 40) * 4;
            *(float4*)&smem[row * 164 + col] = vs4[i];
        }
    }
    __syncthreads();

    f32x4 sac[NCAP];
    #pragma unroll
    for (int n = 0; n < NCAP; ++n) sac[n] = zf;

    // ---- load fragments for j0 ----
    bf16x8 fw[NCAP]; bf16x8 fx;
    fx = zb;
    #pragma unroll
    for (int n = 0; n < NCAP; ++n) fw[n] = zb;
    if (act) {
        if (use_xt) {
            fx = *(const bf16x8*)&x_t[((size_t)j0 * 4 + bh * 2 + bg_l) * 256 + lane * 8];
        } else {
            const float* xp = x + ((size_t)b * IC + j0) * 16 + kq * 8;
            float4 x0 = *(const float4*)xp, x1 = *(const float4*)(xp + 4);
            fx[0] = (short)f2bf(x0.x); fx[1] = (short)f2bf(x0.y);
            fx[2] = (short)f2bf(x0.z); fx[3] = (short)f2bf(x0.w);
            fx[4] = (short)f2bf(x1.x); fx[5] = (short)f2bf(x1.y);
            fx[6] = (short)f2bf(x1.z); fx[7] = (short)f2bf(x1.w);
        }
        #pragma unroll
        for (int n = 0; n < NCAP; ++n)
            fw[n] = *(const bf16x8*)&w_t[((size_t)j0 * NCAP + n) * 256 + lane * 8];
    }

    #pragma unroll
    for (int jt = 0; jt < 3; ++jt) {
        // ---- prefetch j+1 ----
        bf16x8 nw_[NCAP]; bf16x8 nx;
        nx = zb;
        #pragma unroll
        for (int n = 0; n < NCAP; ++n) nw_[n] = zb;
        if (jt < 2) {
            const int j1 = j0 + jt + 1;
            if (act) {
                if (use_xt) {
                    nx = *(const bf16x8*)&x_t[((size_t)j1 * 4 + bh * 2 + bg_l) * 256 + lane * 8];
                } else {
                    const float* xp = x + ((size_t)b * IC + j1) * 16 + kq * 8;
                    float4 x0 = *(const float4*)xp, x1 = *(const float4*)(xp + 4);
                    nx[0] = (short)f2bf(x0.x); nx[1] = (short)f2bf(x0.y);
                    nx[2] = (short)f2bf(x0.z); nx[3] = (short)f2bf(x0.w);
                    nx[4] = (short)f2bf(x1.x); nx[5] = (short)f2bf(x1.y);
                    nx[6] = (short)f2bf(x1.z); nx[7] = (short)f2bf(x1.w);
                }
                #pragma unroll
                for (int n = 0; n < NCAP; ++n)
                    nw_[n] = *(const bf16x8*)&w_t[((size_t)j1 * NCAP + n) * 256 + lane * 8];
            }
        }

        // ---- compute on current j ----
        if (iter == 0) {
            #pragma unroll
            for (int n = 0; n < NCAP; ++n) {
                f32x4 u4 = __builtin_amdgcn_mfma_f32_16x16x32_bf16(fw[n], fx, zf, 0, 0, 0);
                sac[n][0] = fmaf(0.1f, u4[0], sac[n][0]);
                sac[n][1] = fmaf(0.1f, u4[1], sac[n][1]);
                sac[n][2] = fmaf(0.1f, u4[2], sac[n][2]);
                sac[n][3] = fmaf(0.1f, u4[3], sac[n][3]);
            }
        } else {
            // pass 1: routing logits (u transient)
            float bb_[NCAP];
            #pragma unroll
            for (int n = 0; n < NCAP; ++n) {
                f32x4 u4 = __builtin_amdgcn_mfma_f32_16x16x32_bf16(fw[n], fx, zf, 0, 0, 0);
                f32x4 vvn = *(const f32x4*)&smem[vrow + n * 16 + kq * 4];
                float p = u4[0] * vvn[0] + u4[1] * vvn[1]
                        + u4[2] * vvn[2] + u4[3] * vvn[3];
                p += __shfl_xor(p, 16);
                p += __shfl_xor(p, 32);
                bb_[n] = p;
            }
            float ssum = 0.f;
            float c[NCAP];
            #pragma unroll
            for (int n = 0; n < NCAP; ++n) { c[n] = __expf(bb_[n]); ssum += c[n]; }
            const float inv = 1.0f / ssum;
            // pass 2: re-MFMA and accumulate
            #pragma unroll
            for (int n = 0; n < NCAP; ++n) {
                f32x4 u4 = __builtin_amdgcn_mfma_f32_16x16x32_bf16(fw[n], fx, zf, 0, 0, 0);
                const float cn = c[n] * inv;
                sac[n][0] = fmaf(cn, u4[0], sac[n][0]);
                sac[n][1] = fmaf(cn, u4[1], sac[n][1]);
                sac[n][2] = fmaf(cn, u4[2], sac[n][2]);
                sac[n][3] = fmaf(cn, u4[3], sac[n][3]);
            }
        }

        // rotate buffers (vanishes under full unroll)
        fx = nx;
        #pragma unroll
        for (int n = 0; n < NCAP; ++n) fw[n] = nw_[n];
    }

    // ---- combine jw=1 into jw=0 and store partial ----
    __syncthreads();                       // everyone done reading vv region
    const int sb = (bg_l * 16 + bl) * 164 + kq * 4;
    if (jw == 1) {
        #pragma unroll
        for (int n = 0; n < NCAP; ++n)
            *(f32x4*)&smem[sb + n * 16] = sac[n];
    }
    __syncthreads();
    if (jw == 0) {
        float* pp = part + (size_t)logical * 5120;
        #pragma unroll
        for (int n = 0; n < NCAP; ++n) {
            f32x4 t = *(const f32x4*)&smem[sb + n * 16];
            t[0] += sac[n][0]; t[1] += sac[n][1];
            t[2] += sac[n][2]; t[3] += sac[n][3];
            *(f32x4*)&pp[(bg_l * 16 + bl) * 160 + n * 16 + kq * 4] = t;
        }
    }
}

// Fused reduce (NSLOT slots -> s) + squash + vsum/out. Grid 160 x 1024:
// 16-way k-split; each rq-group covers 72 of the 1152 jg-pair super-slots.
__global__ __launch_bounds__(1024) void reduce_kernel(
    const float* __restrict__ part, float* __restrict__ vsum,
    float* __restrict__ out, int iter)
{
    __shared__ float lds[15 * 64];
    const int tid = threadIdx.x;
    const int gi = tid & 63, rq = tid >> 6;       // rq 0..15
    const int g  = blockIdx.x * 64 + gi;          // 0..10239
    const float* p0 = part + g;                   // slot parity encodes bh
    float acc = 0.f;
    for (int k = rq * 72; k < rq * 72 + 72; ++k)  // 16*72 = 1152 jg pairs
        acc += p0[(size_t)k * 10240];
    if (rq > 0) lds[(rq - 1) * 64 + gi] = acc;
    __syncthreads();
    if (rq == 0) {
        #pragma unroll
        for (int r = 0; r < 15; ++r) acc += lds[r * 64 + gi];
        float sq = acc * acc;                     // squash over o = bits 0..3
        sq += __shfl_xor(sq, 1);
        sq += __shfl_xor(sq, 2);
        sq += __shfl_xor(sq, 4);
        sq += __shfl_xor(sq, 8);
        float scale = (sq / (1.f + sq)) / sqrtf(sq + 1e-7f);
        float v = scale * acc;
        if (iter == 2)      out[g] = v;
        else if (iter == 0) vsum[g] = v;
        else                vsum[g] += v;
    }
}

extern "C" void kernel_launch(void* const* d_in, const int* in_sizes, int n_in,
                              void* d_out, int out_size, void* d_ws, size_t ws_size,
                              hipStream_t stream) {
    (void)in_sizes; (void)n_in; (void)out_size;
    const float* x = (const float*)d_in[0];   // [64, 6912, 16]
    const float* W = (const float*)d_in[1];   // [10, 6912, 16, 16]
    float* out = (float*)d_out;               // [64, 10, 16]

    const size_t wt_sh = (size_t)IC * NCAP * 256;   // shorts (35.4 MB)
    const size_t xt_sh = (size_t)IC * 4 * 256;      // shorts (14.2 MB)
    const size_t part_f = (size_t)NSLOT * 5120;     // floats (47.2 MB)
    const size_t need_xt = wt_sh * 2 + xt_sh * 2 + part_f * 4 + 10240 * 4;

    int use_xt = (ws_size >= need_xt) ? 1 : 0;
    unsigned short* w_t = (unsigned short*)d_ws;
    unsigned short* x_t = use_xt ? (w_t + wt_sh) : nullptr;
    float* part = (float*)(use_xt ? (void*)(x_t + xt_sh) : (void*)(w_t + wt_sh));
    float* vsum = part + part_f;

    prep_kernel<<<use_xt ? (1024 + IC) : 1024, 256, 0, stream>>>(x, W, w_t, x_t, use_xt);
    for (int iter = 0; iter < 3; ++iter) {
        sweep_kernel<<<NSLOT, 256, 0, stream>>>(x, x_t, w_t, vsum, part, iter, use_xt);
        reduce_kernel<<<160, 1024, 0, stream>>>(part, vsum, out, iter);
    }
}

// Round 4
// 284.608 us; speedup vs baseline: 2.8068x; 2.8068x over previous
//
#include <hip/hip_runtime.h>
#include <math.h>

#define NCAP 10
#define IC   6912
#define NJG  1152                 // j-groups (6 j each) -> 3x more waves in flight
#define NSLOT (NJG * 2)           // part slots (2304 = 8 * 288, XCD-swizzlable)
#define WPAIRS ((IC * NCAP) / 2)  // 34560 W tile-pairs

typedef __attribute__((ext_vector_type(4))) float f32x4;
typedef __attribute__((ext_vector_type(8))) short bf16x8;

// fp32 -> bf16 RNE
static __device__ inline unsigned short f2bf(float f) {
    unsigned int u = __float_as_uint(f);
    unsigned int r = u + 0x7FFFu + ((u >> 16) & 1u);
    return (unsigned short)(r >> 16);
}

// Prep: blocks <1024 transpose W into MFMA A-fragment order (R5-proven body);
// blocks >=1024 (one per j) convert x into B-fragment order bf16.
__global__ __launch_bounds__(256) void prep_kernel(
    const float* __restrict__ x, const float* __restrict__ W,
    unsigned short* __restrict__ w_t, unsigned short* __restrict__ x_t,
    int use_xt)
{
    __shared__ float lds[4 * 1312];
    const int tid  = threadIdx.x;
    const int lane = tid & 63;
    const int wv   = tid >> 6;

    if (blockIdx.x < 1024) {
        float* L0 = lds + wv * 1312;
        const int gw = blockIdx.x * 4 + wv;
        const int lr  = lane & 31;
        const int reg = lane >> 5;
        const int ia  = lr >> 2, oq = lr & 3;
        const int o   = lr & 15, kq2 = lr >> 4;
        const float4* W4 = (const float4*)W;
        int itc = 0;
        for (int p = gw; p < WPAIRS; p += 4096, ++itc) {
            float* L = L0 + (itc & 1) * 656;
            const int tl = p * 2 + reg;          // tile id = j*10 + n
            const int n = tl % 10, j = tl / 10;
            const float4* src = W4 + ((size_t)n * IC + j) * 64;
            float4 a = src[lr];
            float4 c = src[lr + 32];
            *(float4*)&L[reg * 328 + ia * 20 + oq * 4] = a;
            *(float4*)&L[reg * 328 + (ia + 8) * 20 + oq * 4] = c;
            bf16x8 fr;
            #pragma unroll
            for (int t = 0; t < 8; ++t)
                fr[t] = (short)f2bf(L[reg * 328 + (kq2 * 8 + t) * 20 + o]);
            *(bf16x8*)&w_t[(size_t)tl * 256 + lr * 8] = fr;
        }
    } else if (use_xt) {
        const int j  = blockIdx.x - 1024;        // 0..6911
        const int bg = wv;                       // b-group of 16
        if (lane < 32) {
            const int bl = lane & 15, kq = lane >> 4;
            const float* xp = x + ((size_t)(bg * 16 + bl) * IC + j) * 16 + kq * 8;
            float4 x0 = *(const float4*)xp;
            float4 x1 = *(const float4*)(xp + 4);
            bf16x8 fr;
            fr[0] = (short)f2bf(x0.x); fr[1] = (short)f2bf(x0.y);
            fr[2] = (short)f2bf(x0.z); fr[3] = (short)f2bf(x0.w);
            fr[4] = (short)f2bf(x1.x); fr[5] = (short)f2bf(x1.y);
            fr[6] = (short)f2bf(x1.z); fr[7] = (short)f2bf(x1.w);
            *(bf16x8*)&x_t[((size_t)j * 4 + bg) * 256 + lane * 8] = fr;
        }
    }
}

// Routing sweep, two-pass MFMA + explicit double buffer, vv in LDS.
// Block 256 = 4 waves = bg_l(2) x jw(2); covers 32 b's (bh half), 6 j's
// (3 per jw-wave). R0/R2-proven body with the R3 fine j-tiling (grid 2304
// -> ~56% occupancy). launch_bounds is (256,3): R3's (256,6) capped the
// allocator at 85 VGPRs and SPILLED the fragment arrays (VGPR 84->40,
// WRITE_SIZE 103->559 MB, 226us). 84 VGPRs already gives 6 waves/SIMD.
// Bijective XCD swizzle keeps the bh=0/1 pair of each jg on one XCD L2.
// Layouts (R2/R5-proven): A[m=o=lane&15][k=(lane>>4)*8+t], B[k][b=lane&15],
// D col=lane&15(=b) row=(lane>>4)*4+reg(=o); K 16->32 zero-padded via zero
// fragments on lanes>=32 (outputs on ALL lanes are valid).
__global__ __launch_bounds__(256, 3) void sweep_kernel(
    const float* __restrict__ x, const unsigned short* __restrict__ x_t,
    const unsigned short* __restrict__ w_t, const float* __restrict__ vsum,
    float* __restrict__ part, int iter, int use_xt)
{
    __shared__ float smem[32 * 164];      // vv tile during loop; cbuf at end

    const int tid  = threadIdx.x;
    const int lane = tid & 63;
    const int wave = tid >> 6;
    const int bl   = lane & 15;
    const int kq   = lane >> 4;
    const bool act = (lane < 32);
    // XCD swizzle: logical slot; pairs (2k,2k+1) come from blockIdx b,b+8.
    const int logical = ((int)blockIdx.x & 7) * (NSLOT / 8) + ((int)blockIdx.x >> 3);
    const int bh   = logical & 1;
    const int jg   = logical >> 1;
    const int bg_l = wave & 1;
    const int jw   = wave >> 1;
    const int b    = bh * 32 + bg_l * 16 + bl;
    const int j0   = jg * 6 + jw * 3;
    const int vrow = (bg_l * 16 + bl) * 164;

    const f32x4 zf = (f32x4){0.f, 0.f, 0.f, 0.f};
    const bf16x8 zb = (bf16x8){0, 0, 0, 0, 0, 0, 0, 0};

    if (iter > 0) {
        // vectorized vsum -> LDS (float4, 5 per thread)
        const float4* vs4 = (const float4*)(vsum + bh * 5120);
        for (int i = tid; i < 1280; i += 256) {
            const int row = i / 40, col = (i % 40) * 4;
            *(float4*)&smem[row * 164 + col] = vs4[i];
        }
    }
    __syncthreads();

    f32x4 sac[NCAP];
    #pragma unroll
    for (int n = 0; n < NCAP; ++n) sac[n] = zf;

    // ---- load fragments for j0 ----
    bf16x8 fw[NCAP]; bf16x8 fx;
    fx = zb;
    #pragma unroll
    for (int n = 0; n < NCAP; ++n) fw[n] = zb;
    if (act) {
        if (use_xt) {
            fx = *(const bf16x8*)&x_t[((size_t)j0 * 4 + bh * 2 + bg_l) * 256 + lane * 8];
        } else {
            const float* xp = x + ((size_t)b * IC + j0) * 16 + kq * 8;
            float4 x0 = *(const float4*)xp, x1 = *(const float4*)(xp + 4);
            fx[0] = (short)f2bf(x0.x); fx[1] = (short)f2bf(x0.y);
            fx[2] = (short)f2bf(x0.z); fx[3] = (short)f2bf(x0.w);
            fx[4] = (short)f2bf(x1.x); fx[5] = (short)f2bf(x1.y);
            fx[6] = (short)f2bf(x1.z); fx[7] = (short)f2bf(x1.w);
        }
        #pragma unroll
        for (int n = 0; n < NCAP; ++n)
            fw[n] = *(const bf16x8*)&w_t[((size_t)j0 * NCAP + n) * 256 + lane * 8];
    }

    #pragma unroll
    for (int jt = 0; jt < 3; ++jt) {
        // ---- prefetch j+1 ----
        bf16x8 nw_[NCAP]; bf16x8 nx;
        nx = zb;
        #pragma unroll
        for (int n = 0; n < NCAP; ++n) nw_[n] = zb;
        if (jt < 2) {
            const int j1 = j0 + jt + 1;
            if (act) {
                if (use_xt) {
                    nx = *(const bf16x8*)&x_t[((size_t)j1 * 4 + bh * 2 + bg_l) * 256 + lane * 8];
                } else {
                    const float* xp = x + ((size_t)b * IC + j1) * 16 + kq * 8;
                    float4 x0 = *(const float4*)xp, x1 = *(const float4*)(xp + 4);
                    nx[0] = (short)f2bf(x0.x); nx[1] = (short)f2bf(x0.y);
                    nx[2] = (short)f2bf(x0.z); nx[3] = (short)f2bf(x0.w);
                    nx[4] = (short)f2bf(x1.x); nx[5] = (short)f2bf(x1.y);
                    nx[6] = (short)f2bf(x1.z); nx[7] = (short)f2bf(x1.w);
                }
                #pragma unroll
                for (int n = 0; n < NCAP; ++n)
                    nw_[n] = *(const bf16x8*)&w_t[((size_t)j1 * NCAP + n) * 256 + lane * 8];
            }
        }

        // ---- compute on current j ----
        if (iter == 0) {
            #pragma unroll
            for (int n = 0; n < NCAP; ++n) {
                f32x4 u4 = __builtin_amdgcn_mfma_f32_16x16x32_bf16(fw[n], fx, zf, 0, 0, 0);
                sac[n][0] = fmaf(0.1f, u4[0], sac[n][0]);
                sac[n][1] = fmaf(0.1f, u4[1], sac[n][1]);
                sac[n][2] = fmaf(0.1f, u4[2], sac[n][2]);
                sac[n][3] = fmaf(0.1f, u4[3], sac[n][3]);
            }
        } else {
            // pass 1: routing logits (u transient)
            float bb_[NCAP];
            #pragma unroll
            for (int n = 0; n < NCAP; ++n) {
                f32x4 u4 = __builtin_amdgcn_mfma_f32_16x16x32_bf16(fw[n], fx, zf, 0, 0, 0);
                f32x4 vvn = *(const f32x4*)&smem[vrow + n * 16 + kq * 4];
                float p = u4[0] * vvn[0] + u4[1] * vvn[1]
                        + u4[2] * vvn[2] + u4[3] * vvn[3];
                p += __shfl_xor(p, 16);
                p += __shfl_xor(p, 32);
                bb_[n] = p;
            }
            float ssum = 0.f;
            float c[NCAP];
            #pragma unroll
            for (int n = 0; n < NCAP; ++n) { c[n] = __expf(bb_[n]); ssum += c[n]; }
            const float inv = 1.0f / ssum;
            // pass 2: re-MFMA and accumulate
            #pragma unroll
            for (int n = 0; n < NCAP; ++n) {
                f32x4 u4 = __builtin_amdgcn_mfma_f32_16x16x32_bf16(fw[n], fx, zf, 0, 0, 0);
                const float cn = c[n] * inv;
                sac[n][0] = fmaf(cn, u4[0], sac[n][0]);
                sac[n][1] = fmaf(cn, u4[1], sac[n][1]);
                sac[n][2] = fmaf(cn, u4[2], sac[n][2]);
                sac[n][3] = fmaf(cn, u4[3], sac[n][3]);
            }
        }

        // rotate buffers (vanishes under full unroll)
        fx = nx;
        #pragma unroll
        for (int n = 0; n < NCAP; ++n) fw[n] = nw_[n];
    }

    // ---- combine jw=1 into jw=0 and store partial ----
    __syncthreads();                       // everyone done reading vv region
    const int sb = (bg_l * 16 + bl) * 164 + kq * 4;
    if (jw == 1) {
        #pragma unroll
        for (int n = 0; n < NCAP; ++n)
            *(f32x4*)&smem[sb + n * 16] = sac[n];
    }
    __syncthreads();
    if (jw == 0) {
        float* pp = part + (size_t)logical * 5120;
        #pragma unroll
        for (int n = 0; n < NCAP; ++n) {
            f32x4 t = *(const f32x4*)&smem[sb + n * 16];
            t[0] += sac[n][0]; t[1] += sac[n][1];
            t[2] += sac[n][2]; t[3] += sac[n][3];
            *(f32x4*)&pp[(bg_l * 16 + bl) * 160 + n * 16 + kq * 4] = t;
        }
    }
}

// Fused reduce (NSLOT slots -> s) + squash + vsum/out. Grid 160 x 1024:
// 16-way k-split; each rq-group covers 72 of the 1152 jg-pair super-slots.
__global__ __launch_bounds__(1024) void reduce_kernel(
    const float* __restrict__ part, float* __restrict__ vsum,
    float* __restrict__ out, int iter)
{
    __shared__ float lds[15 * 64];
    const int tid = threadIdx.x;
    const int gi = tid & 63, rq = tid >> 6;       // rq 0..15
    const int g  = blockIdx.x * 64 + gi;          // 0..10239
    const float* p0 = part + g;                   // slot parity encodes bh
    float acc = 0.f;
    for (int k = rq * 72; k < rq * 72 + 72; ++k)  // 16*72 = 1152 jg pairs
        acc += p0[(size_t)k * 10240];
    if (rq > 0) lds[(rq - 1) * 64 + gi] = acc;
    __syncthreads();
    if (rq == 0) {
        #pragma unroll
        for (int r = 0; r < 15; ++r) acc += lds[r * 64 + gi];
        float sq = acc * acc;                     // squash over o = bits 0..3
        sq += __shfl_xor(sq, 1);
        sq += __shfl_xor(sq, 2);
        sq += __shfl_xor(sq, 4);
        sq += __shfl_xor(sq, 8);
        float scale = (sq / (1.f + sq)) / sqrtf(sq + 1e-7f);
        float v = scale * acc;
        if (iter == 2)      out[g] = v;
        else if (iter == 0) vsum[g] = v;
        else                vsum[g] += v;
    }
}

extern "C" void kernel_launch(void* const* d_in, const int* in_sizes, int n_in,
                              void* d_out, int out_size, void* d_ws, size_t ws_size,
                              hipStream_t stream) {
    (void)in_sizes; (void)n_in; (void)out_size;
    const float* x = (const float*)d_in[0];   // [64, 6912, 16]
    const float* W = (const float*)d_in[1];   // [10, 6912, 16, 16]
    float* out = (float*)d_out;               // [64, 10, 16]

    const size_t wt_sh = (size_t)IC * NCAP * 256;   // shorts (35.4 MB)
    const size_t xt_sh = (size_t)IC * 4 * 256;      // shorts (14.2 MB)
    const size_t part_f = (size_t)NSLOT * 5120;     // floats (47.2 MB)
    const size_t need_xt = wt_sh * 2 + xt_sh * 2 + part_f * 4 + 10240 * 4;

    int use_xt = (ws_size >= need_xt) ? 1 : 0;
    unsigned short* w_t = (unsigned short*)d_ws;
    unsigned short* x_t = use_xt ? (w_t + wt_sh) : nullptr;
    float* part = (float*)(use_xt ? (void*)(x_t + xt_sh) : (void*)(w_t + wt_sh));
    float* vsum = part + part_f;

    prep_kernel<<<use_xt ? (1024 + IC) : 1024, 256, 0, stream>>>(x, W, w_t, x_t, use_xt);
    for (int iter = 0; iter < 3; ++iter) {
        sweep_kernel<<<NSLOT, 256, 0, stream>>>(x, x_t, w_t, vsum, part, iter, use_xt);
        reduce_kernel<<<160, 1024, 0, stream>>>(part, vsum, out, iter);
    }
}

// Round 5
// 227.783 us; speedup vs baseline: 3.5070x; 1.2495x over previous
//
#include <hip/hip_runtime.h>
#include <math.h>

#define NCAP 10
#define IC   6912
#define NJG  1152                 // j-groups (6 j each)
#define NSLOT (NJG * 2)           // part slots (2304 = 8 * 288, XCD-swizzlable)
#define WPAIRS ((IC * NCAP) / 2)  // 34560 W tile-pairs

typedef __attribute__((ext_vector_type(4))) float f32x4;
typedef __attribute__((ext_vector_type(8))) short bf16x8;

// fp32 -> bf16 RNE
static __device__ inline unsigned short f2bf(float f) {
    unsigned int u = __float_as_uint(f);
    unsigned int r = u + 0x7FFFu + ((u >> 16) & 1u);
    return (unsigned short)(r >> 16);
}

// Prep: blocks <1024 transpose W into MFMA A-fragment order (R5-proven body);
// blocks >=1024 (one per j) convert x into B-fragment order bf16. UNCHANGED.
__global__ __launch_bounds__(256) void prep_kernel(
    const float* __restrict__ x, const float* __restrict__ W,
    unsigned short* __restrict__ w_t, unsigned short* __restrict__ x_t,
    int use_xt)
{
    __shared__ float lds[4 * 1312];
    const int tid  = threadIdx.x;
    const int lane = tid & 63;
    const int wv   = tid >> 6;

    if (blockIdx.x < 1024) {
        float* L0 = lds + wv * 1312;
        const int gw = blockIdx.x * 4 + wv;
        const int lr  = lane & 31;
        const int reg = lane >> 5;
        const int ia  = lr >> 2, oq = lr & 3;
        const int o   = lr & 15, kq2 = lr >> 4;
        const float4* W4 = (const float4*)W;
        int itc = 0;
        for (int p = gw; p < WPAIRS; p += 4096, ++itc) {
            float* L = L0 + (itc & 1) * 656;
            const int tl = p * 2 + reg;          // tile id = j*10 + n
            const int n = tl % 10, j = tl / 10;
            const float4* src = W4 + ((size_t)n * IC + j) * 64;
            float4 a = src[lr];
            float4 c = src[lr + 32];
            *(float4*)&L[reg * 328 + ia * 20 + oq * 4] = a;
            *(float4*)&L[reg * 328 + (ia + 8) * 20 + oq * 4] = c;
            bf16x8 fr;
            #pragma unroll
            for (int t = 0; t < 8; ++t)
                fr[t] = (short)f2bf(L[reg * 328 + (kq2 * 8 + t) * 20 + o]);
            *(bf16x8*)&w_t[(size_t)tl * 256 + lr * 8] = fr;
        }
    } else if (use_xt) {
        const int j  = blockIdx.x - 1024;        // 0..6911
        const int bg = wv;                       // b-group of 16
        if (lane < 32) {
            const int bl = lane & 15, kq = lane >> 4;
            const float* xp = x + ((size_t)(bg * 16 + bl) * IC + j) * 16 + kq * 8;
            float4 x0 = *(const float4*)xp;
            float4 x1 = *(const float4*)(xp + 4);
            bf16x8 fr;
            fr[0] = (short)f2bf(x0.x); fr[1] = (short)f2bf(x0.y);
            fr[2] = (short)f2bf(x0.z); fr[3] = (short)f2bf(x0.w);
            fr[4] = (short)f2bf(x1.x); fr[5] = (short)f2bf(x1.y);
            fr[6] = (short)f2bf(x1.z); fr[7] = (short)f2bf(x1.w);
            *(bf16x8*)&x_t[((size_t)j * 4 + bg) * 256 + lane * 8] = fr;
        }
    }
}

// Routing sweep, RESTRUCTURED for register pressure (R4 post-mortem: true
// live state ~148 regs (84 arch + 40 acc + ...) capped residency at 3
// waves/SIMD regardless of grid; occupancy stuck ~24% at both 768 and 2304
// blocks).
// New decomposition: 4 waves = bg_l(2) x nh(2). Each wave: 16 b's, FIVE
// capsules (nh half), all 6 j's. Per j: 5 MFMAs -> u[5] KEPT in registers
// and reused for both the logit dot and the c-weighted accumulation (the
// re-MFMA pass is gone; MFMA count halves). fw shrinks to 5 fragments
// refilled in place. Softmax couples the nh halves only through
// sum(exp): one partial sum per (bg_l,b) exchanged via a parity-double-
// buffered 128-float LDS strip -> ONE barrier per j-iter. nh waves own
// disjoint (b,n) outputs -> direct store, no combine epilogue.
// Live state ~90 regs -> ~5 waves/SIMD. launch_bounds(256,4) caps at 128
// (R3 lesson: never cap below the structural need; est. 90 << 128).
// Layouts (R2/R5-proven, unchanged): A[m=o=lane&15][k=(lane>>4)*8+t],
// B[k][b=lane&15], D col=lane&15(=b) row=(lane>>4)*4+reg(=o); K 16->32
// zero-padded via zero fragments on lanes>=32 (D valid on ALL lanes).
__global__ __launch_bounds__(256, 4) void sweep_kernel(
    const float* __restrict__ x, const unsigned short* __restrict__ x_t,
    const unsigned short* __restrict__ w_t, const float* __restrict__ vsum,
    float* __restrict__ part, int iter, int use_xt)
{
    __shared__ float smem[32 * 164 + 128];   // vv tile + exchange strip

    const int tid  = threadIdx.x;
    const int lane = tid & 63;
    const int wave = tid >> 6;
    const int bl   = lane & 15;
    const int kq   = lane >> 4;          // 0..3: o-group of D rows
    const bool act = (lane < 32);
    // XCD swizzle: logical slot; pairs (2k,2k+1) come from blockIdx b,b+8.
    const int logical = ((int)blockIdx.x & 7) * (NSLOT / 8) + ((int)blockIdx.x >> 3);
    const int bh   = logical & 1;
    const int jg   = logical >> 1;
    const int bg_l = wave & 1;
    const int nh   = wave >> 1;          // capsule half: n = nh*5 + p
    const int b    = bh * 32 + bg_l * 16 + bl;
    const int j0   = jg * 6;
    const int vrow = (bg_l * 16 + bl) * 164;
    float* exbuf = smem + 5248;          // [parity 2][nh 2][32]

    const f32x4 zf = (f32x4){0.f, 0.f, 0.f, 0.f};
    const bf16x8 zb = (bf16x8){0, 0, 0, 0, 0, 0, 0, 0};

    if (iter > 0) {
        // vectorized vsum -> LDS (float4, 5 per thread)
        const float4* vs4 = (const float4*)(vsum + bh * 5120);
        for (int i = tid; i < 1280; i += 256) {
            const int row = i / 40, col = (i % 40) * 4;
            *(float4*)&smem[row * 164 + col] = vs4[i];
        }
    }
    __syncthreads();

    f32x4 sac[5];
    #pragma unroll
    for (int p = 0; p < 5; ++p) sac[p] = zf;

    // ---- prologue: fragments for j0 ----
    bf16x8 fw[5]; bf16x8 fx;
    fx = zb;
    #pragma unroll
    for (int p = 0; p < 5; ++p) fw[p] = zb;
    if (act) {
        if (use_xt) {
            fx = *(const bf16x8*)&x_t[((size_t)j0 * 4 + bh * 2 + bg_l) * 256 + lane * 8];
        } else {
            const float* xp = x + ((size_t)b * IC + j0) * 16 + kq * 8;
            float4 x0 = *(const float4*)xp, x1 = *(const float4*)(xp + 4);
            fx[0] = (short)f2bf(x0.x); fx[1] = (short)f2bf(x0.y);
            fx[2] = (short)f2bf(x0.z); fx[3] = (short)f2bf(x0.w);
            fx[4] = (short)f2bf(x1.x); fx[5] = (short)f2bf(x1.y);
            fx[6] = (short)f2bf(x1.z); fx[7] = (short)f2bf(x1.w);
        }
        #pragma unroll
        for (int p = 0; p < 5; ++p)
            fw[p] = *(const bf16x8*)&w_t[((size_t)j0 * NCAP + nh * 5 + p) * 256 + lane * 8];
    }

    #pragma unroll
    for (int jt = 0; jt < 6; ++jt) {
        const int j1 = j0 + jt + 1;          // only used when jt < 5

        // prefetch next x fragment
        bf16x8 nx = zb;
        if (jt < 5 && act) {
            if (use_xt) {
                nx = *(const bf16x8*)&x_t[((size_t)j1 * 4 + bh * 2 + bg_l) * 256 + lane * 8];
            } else {
                const float* xp = x + ((size_t)b * IC + j1) * 16 + kq * 8;
                float4 x0 = *(const float4*)xp, x1 = *(const float4*)(xp + 4);
                nx[0] = (short)f2bf(x0.x); nx[1] = (short)f2bf(x0.y);
                nx[2] = (short)f2bf(x0.z); nx[3] = (short)f2bf(x0.w);
                nx[4] = (short)f2bf(x1.x); nx[5] = (short)f2bf(x1.y);
                nx[6] = (short)f2bf(x1.z); nx[7] = (short)f2bf(x1.w);
            }
        }

        // ---- single MFMA pass: u kept in registers ----
        f32x4 u[5];
        #pragma unroll
        for (int p = 0; p < 5; ++p)
            u[p] = __builtin_amdgcn_mfma_f32_16x16x32_bf16(fw[p], fx, zf, 0, 0, 0);

        // refill fw in place for next j (in flight during softmax/accum)
        if (jt < 5 && act) {
            #pragma unroll
            for (int p = 0; p < 5; ++p)
                fw[p] = *(const bf16x8*)&w_t[((size_t)j1 * NCAP + nh * 5 + p) * 256 + lane * 8];
        }

        if (iter == 0) {
            #pragma unroll
            for (int p = 0; p < 5; ++p) {
                sac[p][0] = fmaf(0.1f, u[p][0], sac[p][0]);
                sac[p][1] = fmaf(0.1f, u[p][1], sac[p][1]);
                sac[p][2] = fmaf(0.1f, u[p][2], sac[p][2]);
                sac[p][3] = fmaf(0.1f, u[p][3], sac[p][3]);
            }
        } else {
            // logits for this wave's 5 capsules
            float cc[5];
            #pragma unroll
            for (int p = 0; p < 5; ++p) {
                f32x4 vvn = *(const f32x4*)&smem[vrow + (nh * 5 + p) * 16 + kq * 4];
                float pr = u[p][0] * vvn[0] + u[p][1] * vvn[1]
                         + u[p][2] * vvn[2] + u[p][3] * vvn[3];
                pr += __shfl_xor(pr, 16);
                pr += __shfl_xor(pr, 32);
                cc[p] = pr;
            }
            float s5 = 0.f;
            #pragma unroll
            for (int p = 0; p < 5; ++p) { cc[p] = __expf(cc[p]); s5 += cc[p]; }
            // exchange partial exp-sums between nh halves (parity dbuf,
            // one barrier per j-iter; write/read race separated by the
            // NEXT iteration's barrier)
            float* ex = exbuf + (jt & 1) * 64;
            if (kq == 0) ex[nh * 32 + bg_l * 16 + bl] = s5;
            __syncthreads();
            const float so = ex[(1 - nh) * 32 + bg_l * 16 + bl];
            const float inv = 1.0f / (s5 + so);
            #pragma unroll
            for (int p = 0; p < 5; ++p) {
                const float cn = cc[p] * inv;
                sac[p][0] = fmaf(cn, u[p][0], sac[p][0]);
                sac[p][1] = fmaf(cn, u[p][1], sac[p][1]);
                sac[p][2] = fmaf(cn, u[p][2], sac[p][2]);
                sac[p][3] = fmaf(cn, u[p][3], sac[p][3]);
            }
        }

        fx = nx;
    }

    // ---- direct store: nh waves own disjoint capsules, no combine ----
    float* pp = part + (size_t)logical * 5120;
    #pragma unroll
    for (int p = 0; p < 5; ++p)
        *(f32x4*)&pp[(bg_l * 16 + bl) * 160 + (nh * 5 + p) * 16 + kq * 4] = sac[p];
}

// Fused reduce (NSLOT slots -> s) + squash + vsum/out. Grid 160 x 1024:
// 16-way k-split; each rq-group covers 72 of the 1152 jg-pair super-slots.
__global__ __launch_bounds__(1024) void reduce_kernel(
    const float* __restrict__ part, float* __restrict__ vsum,
    float* __restrict__ out, int iter)
{
    __shared__ float lds[15 * 64];
    const int tid = threadIdx.x;
    const int gi = tid & 63, rq = tid >> 6;       // rq 0..15
    const int g  = blockIdx.x * 64 + gi;          // 0..10239
    const float* p0 = part + g;                   // slot parity encodes bh
    float acc = 0.f;
    for (int k = rq * 72; k < rq * 72 + 72; ++k)  // 16*72 = 1152 jg pairs
        acc += p0[(size_t)k * 10240];
    if (rq > 0) lds[(rq - 1) * 64 + gi] = acc;
    __syncthreads();
    if (rq == 0) {
        #pragma unroll
        for (int r = 0; r < 15; ++r) acc += lds[r * 64 + gi];
        float sq = acc * acc;                     // squash over o = bits 0..3
        sq += __shfl_xor(sq, 1);
        sq += __shfl_xor(sq, 2);
        sq += __shfl_xor(sq, 4);
        sq += __shfl_xor(sq, 8);
        float scale = (sq / (1.f + sq)) / sqrtf(sq + 1e-7f);
        float v = scale * acc;
        if (iter == 2)      out[g] = v;
        else if (iter == 0) vsum[g] = v;
        else                vsum[g] += v;
    }
}

extern "C" void kernel_launch(void* const* d_in, const int* in_sizes, int n_in,
                              void* d_out, int out_size, void* d_ws, size_t ws_size,
                              hipStream_t stream) {
    (void)in_sizes; (void)n_in; (void)out_size;
    const float* x = (const float*)d_in[0];   // [64, 6912, 16]
    const float* W = (const float*)d_in[1];   // [10, 6912, 16, 16]
    float* out = (float*)d_out;               // [64, 10, 16]

    const size_t wt_sh = (size_t)IC * NCAP * 256;   // shorts (35.4 MB)
    const size_t xt_sh = (size_t)IC * 4 * 256;      // shorts (14.2 MB)
    const size_t part_f = (size_t)NSLOT * 5120;     // floats (47.2 MB)
    const size_t need_xt = wt_sh * 2 + xt_sh * 2 + part_f * 4 + 10240 * 4;

    int use_xt = (ws_size >= need_xt) ? 1 : 0;
    unsigned short* w_t = (unsigned short*)d_ws;
    unsigned short* x_t = use_xt ? (w_t + wt_sh) : nullptr;
    float* part = (float*)(use_xt ? (void*)(x_t + xt_sh) : (void*)(w_t + wt_sh));
    float* vsum = part + part_f;

    prep_kernel<<<use_xt ? (1024 + IC) : 1024, 256, 0, stream>>>(x, W, w_t, x_t, use_xt);
    for (int iter = 0; iter < 3; ++iter) {
        sweep_kernel<<<NSLOT, 256, 0, stream>>>(x, x_t, w_t, vsum, part, iter, use_xt);
        reduce_kernel<<<160, 1024, 0, stream>>>(part, vsum, out, iter);
    }
}

// Round 6
// 219.873 us; speedup vs baseline: 3.6331x; 1.0360x over previous
//
#include <hip/hip_runtime.h>
#include <math.h>

#define NCAP 10
#define IC   6912
#define NJG  576                  // j-groups (12 j each): 1152 blocks fit fully
                                  // resident (5 blocks/CU VGPR cap -> 1280 max)
#define NSLOT (NJG * 2)           // part slots (1152 = 8 * 144, XCD-swizzlable)
#define JPG  12
#define WPAIRS ((IC * NCAP) / 2)  // 34560 W tile-pairs

typedef __attribute__((ext_vector_type(4))) float f32x4;
typedef __attribute__((ext_vector_type(8))) short bf16x8;

// fp32 -> bf16 RNE
static __device__ inline unsigned short f2bf(float f) {
    unsigned int u = __float_as_uint(f);
    unsigned int r = u + 0x7FFFu + ((u >> 16) & 1u);
    return (unsigned short)(r >> 16);
}

// Prep: blocks <1024 transpose W into MFMA A-fragment order (R5-proven body);
// blocks >=1024 (one per j) convert x into B-fragment order bf16. UNCHANGED.
__global__ __launch_bounds__(256) void prep_kernel(
    const float* __restrict__ x, const float* __restrict__ W,
    unsigned short* __restrict__ w_t, unsigned short* __restrict__ x_t,
    int use_xt)
{
    __shared__ float lds[4 * 1312];
    const int tid  = threadIdx.x;
    const int lane = tid & 63;
    const int wv   = tid >> 6;

    if (blockIdx.x < 1024) {
        float* L0 = lds + wv * 1312;
        const int gw = blockIdx.x * 4 + wv;
        const int lr  = lane & 31;
        const int reg = lane >> 5;
        const int ia  = lr >> 2, oq = lr & 3;
        const int o   = lr & 15, kq2 = lr >> 4;
        const float4* W4 = (const float4*)W;
        int itc = 0;
        for (int p = gw; p < WPAIRS; p += 4096, ++itc) {
            float* L = L0 + (itc & 1) * 656;
            const int tl = p * 2 + reg;          // tile id = j*10 + n
            const int n = tl % 10, j = tl / 10;
            const float4* src = W4 + ((size_t)n * IC + j) * 64;
            float4 a = src[lr];
            float4 c = src[lr + 32];
            *(float4*)&L[reg * 328 + ia * 20 + oq * 4] = a;
            *(float4*)&L[reg * 328 + (ia + 8) * 20 + oq * 4] = c;
            bf16x8 fr;
            #pragma unroll
            for (int t = 0; t < 8; ++t)
                fr[t] = (short)f2bf(L[reg * 328 + (kq2 * 8 + t) * 20 + o]);
            *(bf16x8*)&w_t[(size_t)tl * 256 + lr * 8] = fr;
        }
    } else if (use_xt) {
        const int j  = blockIdx.x - 1024;        // 0..6911
        const int bg = wv;                       // b-group of 16
        if (lane < 32) {
            const int bl = lane & 15, kq = lane >> 4;
            const float* xp = x + ((size_t)(bg * 16 + bl) * IC + j) * 16 + kq * 8;
            float4 x0 = *(const float4*)xp;
            float4 x1 = *(const float4*)(xp + 4);
            bf16x8 fr;
            fr[0] = (short)f2bf(x0.x); fr[1] = (short)f2bf(x0.y);
            fr[2] = (short)f2bf(x0.z); fr[3] = (short)f2bf(x0.w);
            fr[4] = (short)f2bf(x1.x); fr[5] = (short)f2bf(x1.y);
            fr[6] = (short)f2bf(x1.z); fr[7] = (short)f2bf(x1.w);
            *(bf16x8*)&x_t[((size_t)j * 4 + bg) * 256 + lane * 8] = fr;
        }
    }
}

// Routing sweep (R5-proven structure): 4 waves = bg_l(2) x nh(2); each wave
// 16 b's, 5 capsules, all JPG j's. Per j: 5 MFMAs -> u[5] kept in regs,
// reused for logit dot AND accumulation; fw[5] refilled in place; softmax
// couples nh halves only through sum(exp), exchanged via parity-dbuf LDS
// strip (one barrier/j-iter); nh waves own disjoint outputs -> direct store.
// R6 change: JPG 6->12 (grid 2304->1152). Work and registers invariant;
// part buffer halves (47->23.6 MB per sweep write / reduce read) and the
// grid now fits in ONE fully-resident round (1152 <= 1280 = 256CU x 5
// blocks/CU VGPR cap). R4 lesson: TLP is register-capped, not grid-capped.
// Layouts (R2/R5-proven): A[m=o=lane&15][k=(lane>>4)*8+t], B[k][b=lane&15],
// D col=lane&15(=b) row=(lane>>4)*4+reg(=o); K 16->32 zero-padded via zero
// fragments on lanes>=32 (D valid on ALL lanes).
__global__ __launch_bounds__(256, 4) void sweep_kernel(
    const float* __restrict__ x, const unsigned short* __restrict__ x_t,
    const unsigned short* __restrict__ w_t, const float* __restrict__ vsum,
    float* __restrict__ part, int iter, int use_xt)
{
    __shared__ float smem[32 * 164 + 128];   // vv tile + exchange strip

    const int tid  = threadIdx.x;
    const int lane = tid & 63;
    const int wave = tid >> 6;
    const int bl   = lane & 15;
    const int kq   = lane >> 4;          // 0..3: o-group of D rows
    const bool act = (lane < 32);
    // XCD swizzle: logical slot; bh-pairs (2k,2k+1) map to blockIdx b,b+8
    // (same chunk since 144 is even -> same XCD, near-simultaneous).
    const int logical = ((int)blockIdx.x & 7) * (NSLOT / 8) + ((int)blockIdx.x >> 3);
    const int bh   = logical & 1;
    const int jg   = logical >> 1;
    const int bg_l = wave & 1;
    const int nh   = wave >> 1;          // capsule half: n = nh*5 + p
    const int b    = bh * 32 + bg_l * 16 + bl;
    const int j0   = jg * JPG;
    const int vrow = (bg_l * 16 + bl) * 164;
    float* exbuf = smem + 5248;          // [parity 2][nh 2][32]

    const f32x4 zf = (f32x4){0.f, 0.f, 0.f, 0.f};
    const bf16x8 zb = (bf16x8){0, 0, 0, 0, 0, 0, 0, 0};

    if (iter > 0) {
        // vectorized vsum -> LDS (float4, 5 per thread)
        const float4* vs4 = (const float4*)(vsum + bh * 5120);
        for (int i = tid; i < 1280; i += 256) {
            const int row = i / 40, col = (i % 40) * 4;
            *(float4*)&smem[row * 164 + col] = vs4[i];
        }
    }
    __syncthreads();

    f32x4 sac[5];
    #pragma unroll
    for (int p = 0; p < 5; ++p) sac[p] = zf;

    // ---- prologue: fragments for j0 ----
    bf16x8 fw[5]; bf16x8 fx;
    fx = zb;
    #pragma unroll
    for (int p = 0; p < 5; ++p) fw[p] = zb;
    if (act) {
        if (use_xt) {
            fx = *(const bf16x8*)&x_t[((size_t)j0 * 4 + bh * 2 + bg_l) * 256 + lane * 8];
        } else {
            const float* xp = x + ((size_t)b * IC + j0) * 16 + kq * 8;
            float4 x0 = *(const float4*)xp, x1 = *(const float4*)(xp + 4);
            fx[0] = (short)f2bf(x0.x); fx[1] = (short)f2bf(x0.y);
            fx[2] = (short)f2bf(x0.z); fx[3] = (short)f2bf(x0.w);
            fx[4] = (short)f2bf(x1.x); fx[5] = (short)f2bf(x1.y);
            fx[6] = (short)f2bf(x1.z); fx[7] = (short)f2bf(x1.w);
        }
        #pragma unroll
        for (int p = 0; p < 5; ++p)
            fw[p] = *(const bf16x8*)&w_t[((size_t)j0 * NCAP + nh * 5 + p) * 256 + lane * 8];
    }

    #pragma unroll
    for (int jt = 0; jt < JPG; ++jt) {
        const int j1 = j0 + jt + 1;          // only used when jt < JPG-1

        // prefetch next x fragment
        bf16x8 nx = zb;
        if (jt < JPG - 1 && act) {
            if (use_xt) {
                nx = *(const bf16x8*)&x_t[((size_t)j1 * 4 + bh * 2 + bg_l) * 256 + lane * 8];
            } else {
                const float* xp = x + ((size_t)b * IC + j1) * 16 + kq * 8;
                float4 x0 = *(const float4*)xp, x1 = *(const float4*)(xp + 4);
                nx[0] = (short)f2bf(x0.x); nx[1] = (short)f2bf(x0.y);
                nx[2] = (short)f2bf(x0.z); nx[3] = (short)f2bf(x0.w);
                nx[4] = (short)f2bf(x1.x); nx[5] = (short)f2bf(x1.y);
                nx[6] = (short)f2bf(x1.z); nx[7] = (short)f2bf(x1.w);
            }
        }

        // ---- single MFMA pass: u kept in registers ----
        f32x4 u[5];
        #pragma unroll
        for (int p = 0; p < 5; ++p)
            u[p] = __builtin_amdgcn_mfma_f32_16x16x32_bf16(fw[p], fx, zf, 0, 0, 0);

        // refill fw in place for next j (in flight during softmax/accum)
        if (jt < JPG - 1 && act) {
            #pragma unroll
            for (int p = 0; p < 5; ++p)
                fw[p] = *(const bf16x8*)&w_t[((size_t)j1 * NCAP + nh * 5 + p) * 256 + lane * 8];
        }

        if (iter == 0) {
            #pragma unroll
            for (int p = 0; p < 5; ++p) {
                sac[p][0] = fmaf(0.1f, u[p][0], sac[p][0]);
                sac[p][1] = fmaf(0.1f, u[p][1], sac[p][1]);
                sac[p][2] = fmaf(0.1f, u[p][2], sac[p][2]);
                sac[p][3] = fmaf(0.1f, u[p][3], sac[p][3]);
            }
        } else {
            // logits for this wave's 5 capsules
            float cc[5];
            #pragma unroll
            for (int p = 0; p < 5; ++p) {
                f32x4 vvn = *(const f32x4*)&smem[vrow + (nh * 5 + p) * 16 + kq * 4];
                float pr = u[p][0] * vvn[0] + u[p][1] * vvn[1]
                         + u[p][2] * vvn[2] + u[p][3] * vvn[3];
                pr += __shfl_xor(pr, 16);
                pr += __shfl_xor(pr, 32);
                cc[p] = pr;
            }
            float s5 = 0.f;
            #pragma unroll
            for (int p = 0; p < 5; ++p) { cc[p] = __expf(cc[p]); s5 += cc[p]; }
            // exchange partial exp-sums between nh halves (parity dbuf,
            // one barrier per j-iter; the write of parity P at iter jt+2
            // is separated from the read at iter jt by two barriers)
            float* ex = exbuf + (jt & 1) * 64;
            if (kq == 0) ex[nh * 32 + bg_l * 16 + bl] = s5;
            __syncthreads();
            const float so = ex[(1 - nh) * 32 + bg_l * 16 + bl];
            const float inv = 1.0f / (s5 + so);
            #pragma unroll
            for (int p = 0; p < 5; ++p) {
                const float cn = cc[p] * inv;
                sac[p][0] = fmaf(cn, u[p][0], sac[p][0]);
                sac[p][1] = fmaf(cn, u[p][1], sac[p][1]);
                sac[p][2] = fmaf(cn, u[p][2], sac[p][2]);
                sac[p][3] = fmaf(cn, u[p][3], sac[p][3]);
            }
        }

        fx = nx;
    }

    // ---- direct store: nh waves own disjoint capsules, no combine ----
    float* pp = part + (size_t)logical * 5120;
    #pragma unroll
    for (int p = 0; p < 5; ++p)
        *(f32x4*)&pp[(bg_l * 16 + bl) * 160 + (nh * 5 + p) * 16 + kq * 4] = sac[p];
}

// Fused reduce (NSLOT slots -> s) + squash + vsum/out. Grid 160 x 1024:
// 16-way k-split; each rq-group covers 36 of the 576 jg-pair super-slots.
__global__ __launch_bounds__(1024) void reduce_kernel(
    const float* __restrict__ part, float* __restrict__ vsum,
    float* __restrict__ out, int iter)
{
    __shared__ float lds[15 * 64];
    const int tid = threadIdx.x;
    const int gi = tid & 63, rq = tid >> 6;       // rq 0..15
    const int g  = blockIdx.x * 64 + gi;          // 0..10239
    const float* p0 = part + g;                   // slot parity encodes bh
    float acc = 0.f;
    for (int k = rq * 36; k < rq * 36 + 36; ++k)  // 16*36 = 576 jg pairs
        acc += p0[(size_t)k * 10240];
    if (rq > 0) lds[(rq - 1) * 64 + gi] = acc;
    __syncthreads();
    if (rq == 0) {
        #pragma unroll
        for (int r = 0; r < 15; ++r) acc += lds[r * 64 + gi];
        float sq = acc * acc;                     // squash over o = bits 0..3
        sq += __shfl_xor(sq, 1);
        sq += __shfl_xor(sq, 2);
        sq += __shfl_xor(sq, 4);
        sq += __shfl_xor(sq, 8);
        float scale = (sq / (1.f + sq)) / sqrtf(sq + 1e-7f);
        float v = scale * acc;
        if (iter == 2)      out[g] = v;
        else if (iter == 0) vsum[g] = v;
        else                vsum[g] += v;
    }
}

extern "C" void kernel_launch(void* const* d_in, const int* in_sizes, int n_in,
                              void* d_out, int out_size, void* d_ws, size_t ws_size,
                              hipStream_t stream) {
    (void)in_sizes; (void)n_in; (void)out_size;
    const float* x = (const float*)d_in[0];   // [64, 6912, 16]
    const float* W = (const float*)d_in[1];   // [10, 6912, 16, 16]
    float* out = (float*)d_out;               // [64, 10, 16]

    const size_t wt_sh = (size_t)IC * NCAP * 256;   // shorts (35.4 MB)
    const size_t xt_sh = (size_t)IC * 4 * 256;      // shorts (14.2 MB)
    const size_t part_f = (size_t)NSLOT * 5120;     // floats (23.6 MB)
    const size_t need_xt = wt_sh * 2 + xt_sh * 2 + part_f * 4 + 10240 * 4;

    int use_xt = (ws_size >= need_xt) ? 1 : 0;
    unsigned short* w_t = (unsigned short*)d_ws;
    unsigned short* x_t = use_xt ? (w_t + wt_sh) : nullptr;
    float* part = (float*)(use_xt ? (void*)(x_t + xt_sh) : (void*)(w_t + wt_sh));
    float* vsum = part + part_f;

    prep_kernel<<<use_xt ? (1024 + IC) : 1024, 256, 0, stream>>>(x, W, w_t, x_t, use_xt);
    for (int iter = 0; iter < 3; ++iter) {
        sweep_kernel<<<NSLOT, 256, 0, stream>>>(x, x_t, w_t, vsum, part, iter, use_xt);
        reduce_kernel<<<160, 1024, 0, stream>>>(part, vsum, out, iter);
    }
}

// Round 7
// 216.995 us; speedup vs baseline: 3.6813x; 1.0133x over previous
//
#include <hip/hip_runtime.h>
#include <math.h>

#define NCAP 10
#define IC   6912
#define NJG  576                  // j-groups (12 j each): 1152 blocks fit fully
                                  // resident (5 blocks/CU VGPR cap -> 1280 max)
#define NSLOT (NJG * 2)           // part slots (1152 = 8 * 144, XCD-swizzlable)
#define JPG  12
#define WPAIRS ((IC * NCAP) / 2)  // 34560 W tile-pairs
#define WBLK 2048                 // W-transpose blocks (R7: 1024 -> 2048;
                                  // phase was grid-capped at 50% occupancy)

typedef __attribute__((ext_vector_type(4))) float f32x4;
typedef __attribute__((ext_vector_type(8))) short bf16x8;

// fp32 -> bf16 RNE
static __device__ inline unsigned short f2bf(float f) {
    unsigned int u = __float_as_uint(f);
    unsigned int r = u + 0x7FFFu + ((u >> 16) & 1u);
    return (unsigned short)(r >> 16);
}

// Prep: blocks <WBLK transpose W into MFMA A-fragment order (R5-proven body,
// now spread over 2x blocks -> ~4.2 iters/wave, occupancy 50->87% LDS-capped);
// blocks >=WBLK convert x into B-fragment order bf16, 2 j per block (all 64
// lanes active; was 32).
__global__ __launch_bounds__(256) void prep_kernel(
    const float* __restrict__ x, const float* __restrict__ W,
    unsigned short* __restrict__ w_t, unsigned short* __restrict__ x_t,
    int use_xt)
{
    __shared__ float lds[4 * 1312];
    const int tid  = threadIdx.x;
    const int lane = tid & 63;
    const int wv   = tid >> 6;

    if (blockIdx.x < WBLK) {
        float* L0 = lds + wv * 1312;
        const int gw = blockIdx.x * 4 + wv;          // 0..8191
        const int lr  = lane & 31;
        const int reg = lane >> 5;
        const int ia  = lr >> 2, oq = lr & 3;
        const int o   = lr & 15, kq2 = lr >> 4;
        const float4* W4 = (const float4*)W;
        int itc = 0;
        for (int p = gw; p < WPAIRS; p += WBLK * 4, ++itc) {
            float* L = L0 + (itc & 1) * 656;
            const int tl = p * 2 + reg;          // tile id = j*10 + n
            const int n = tl % 10, j = tl / 10;
            const float4* src = W4 + ((size_t)n * IC + j) * 64;
            float4 a = src[lr];
            float4 c = src[lr + 32];
            *(float4*)&L[reg * 328 + ia * 20 + oq * 4] = a;
            *(float4*)&L[reg * 328 + (ia + 8) * 20 + oq * 4] = c;
            bf16x8 fr;
            #pragma unroll
            for (int t = 0; t < 8; ++t)
                fr[t] = (short)f2bf(L[reg * 328 + (kq2 * 8 + t) * 20 + o]);
            *(bf16x8*)&w_t[(size_t)tl * 256 + lr * 8] = fr;
        }
    } else if (use_xt) {
        const int j  = (blockIdx.x - WBLK) * 2 + (lane >> 5);  // 2 j per block
        const int bg = wv;                       // b-group of 16
        const int l31 = lane & 31;
        const int bl = lane & 15, kq = (lane >> 4) & 1;
        const float* xp = x + ((size_t)(bg * 16 + bl) * IC + j) * 16 + kq * 8;
        float4 x0 = *(const float4*)xp;
        float4 x1 = *(const float4*)(xp + 4);
        bf16x8 fr;
        fr[0] = (short)f2bf(x0.x); fr[1] = (short)f2bf(x0.y);
        fr[2] = (short)f2bf(x0.z); fr[3] = (short)f2bf(x0.w);
        fr[4] = (short)f2bf(x1.x); fr[5] = (short)f2bf(x1.y);
        fr[6] = (short)f2bf(x1.z); fr[7] = (short)f2bf(x1.w);
        *(bf16x8*)&x_t[((size_t)j * 4 + bg) * 256 + l31 * 8] = fr;
    }
}

// Routing sweep (R5-proven structure): 4 waves = bg_l(2) x nh(2); each wave
// 16 b's, 5 capsules, all JPG j's. Per j: 5 MFMAs -> u[5] kept in regs,
// reused for logit dot AND accumulation; fw[5] refilled in place; softmax
// couples nh halves only through sum(exp), exchanged via parity-dbuf LDS
// strip (one barrier/j-iter); nh waves own disjoint outputs -> direct store.
// JPG=12 (grid 1152): fully resident in one round (5 blocks/CU VGPR cap).
// R4 lesson: TLP is register-capped, not grid-capped.
// Layouts (R2/R5-proven): A[m=o=lane&15][k=(lane>>4)*8+t], B[k][b=lane&15],
// D col=lane&15(=b) row=(lane>>4)*4+reg(=o); K 16->32 zero-padded via zero
// fragments on lanes>=32 (D valid on ALL lanes).
__global__ __launch_bounds__(256, 4) void sweep_kernel(
    const float* __restrict__ x, const unsigned short* __restrict__ x_t,
    const unsigned short* __restrict__ w_t, const float* __restrict__ vsum,
    float* __restrict__ part, int iter, int use_xt)
{
    __shared__ float smem[32 * 164 + 128];   // vv tile + exchange strip

    const int tid  = threadIdx.x;
    const int lane = tid & 63;
    const int wave = tid >> 6;
    const int bl   = lane & 15;
    const int kq   = lane >> 4;          // 0..3: o-group of D rows
    const bool act = (lane < 32);
    // XCD swizzle: logical slot; bh-pairs (2k,2k+1) map to blockIdx b,b+8
    // (same chunk since 144 is even -> same XCD, near-simultaneous).
    const int logical = ((int)blockIdx.x & 7) * (NSLOT / 8) + ((int)blockIdx.x >> 3);
    const int bh   = logical & 1;
    const int jg   = logical >> 1;
    const int bg_l = wave & 1;
    const int nh   = wave >> 1;          // capsule half: n = nh*5 + p
    const int b    = bh * 32 + bg_l * 16 + bl;
    const int j0   = jg * JPG;
    const int vrow = (bg_l * 16 + bl) * 164;
    float* exbuf = smem + 5248;          // [parity 2][nh 2][32]

    const f32x4 zf = (f32x4){0.f, 0.f, 0.f, 0.f};
    const bf16x8 zb = (bf16x8){0, 0, 0, 0, 0, 0, 0, 0};

    if (iter > 0) {
        // vectorized vsum -> LDS (float4, 5 per thread)
        const float4* vs4 = (const float4*)(vsum + bh * 5120);
        for (int i = tid; i < 1280; i += 256) {
            const int row = i / 40, col = (i % 40) * 4;
            *(float4*)&smem[row * 164 + col] = vs4[i];
        }
    }
    __syncthreads();

    f32x4 sac[5];
    #pragma unroll
    for (int p = 0; p < 5; ++p) sac[p] = zf;

    // ---- prologue: fragments for j0 ----
    bf16x8 fw[5]; bf16x8 fx;
    fx = zb;
    #pragma unroll
    for (int p = 0; p < 5; ++p) fw[p] = zb;
    if (act) {
        if (use_xt) {
            fx = *(const bf16x8*)&x_t[((size_t)j0 * 4 + bh * 2 + bg_l) * 256 + lane * 8];
        } else {
            const float* xp = x + ((size_t)b * IC + j0) * 16 + kq * 8;
            float4 x0 = *(const float4*)xp, x1 = *(const float4*)(xp + 4);
            fx[0] = (short)f2bf(x0.x); fx[1] = (short)f2bf(x0.y);
            fx[2] = (short)f2bf(x0.z); fx[3] = (short)f2bf(x0.w);
            fx[4] = (short)f2bf(x1.x); fx[5] = (short)f2bf(x1.y);
            fx[6] = (short)f2bf(x1.z); fx[7] = (short)f2bf(x1.w);
        }
        #pragma unroll
        for (int p = 0; p < 5; ++p)
            fw[p] = *(const bf16x8*)&w_t[((size_t)j0 * NCAP + nh * 5 + p) * 256 + lane * 8];
    }

    #pragma unroll
    for (int jt = 0; jt < JPG; ++jt) {
        const int j1 = j0 + jt + 1;          // only used when jt < JPG-1

        // prefetch next x fragment
        bf16x8 nx = zb;
        if (jt < JPG - 1 && act) {
            if (use_xt) {
                nx = *(const bf16x8*)&x_t[((size_t)j1 * 4 + bh * 2 + bg_l) * 256 + lane * 8];
            } else {
                const float* xp = x + ((size_t)b * IC + j1) * 16 + kq * 8;
                float4 x0 = *(const float4*)xp, x1 = *(const float4*)(xp + 4);
                nx[0] = (short)f2bf(x0.x); nx[1] = (short)f2bf(x0.y);
                nx[2] = (short)f2bf(x0.z); nx[3] = (short)f2bf(x0.w);
                nx[4] = (short)f2bf(x1.x); nx[5] = (short)f2bf(x1.y);
                nx[6] = (short)f2bf(x1.z); nx[7] = (short)f2bf(x1.w);
            }
        }

        // ---- single MFMA pass: u kept in registers ----
        f32x4 u[5];
        #pragma unroll
        for (int p = 0; p < 5; ++p)
            u[p] = __builtin_amdgcn_mfma_f32_16x16x32_bf16(fw[p], fx, zf, 0, 0, 0);

        // refill fw in place for next j (in flight during softmax/accum)
        if (jt < JPG - 1 && act) {
            #pragma unroll
            for (int p = 0; p < 5; ++p)
                fw[p] = *(const bf16x8*)&w_t[((size_t)j1 * NCAP + nh * 5 + p) * 256 + lane * 8];
        }

        if (iter == 0) {
            #pragma unroll
            for (int p = 0; p < 5; ++p) {
                sac[p][0] = fmaf(0.1f, u[p][0], sac[p][0]);
                sac[p][1] = fmaf(0.1f, u[p][1], sac[p][1]);
                sac[p][2] = fmaf(0.1f, u[p][2], sac[p][2]);
                sac[p][3] = fmaf(0.1f, u[p][3], sac[p][3]);
            }
        } else {
            // logits for this wave's 5 capsules
            float cc[5];
            #pragma unroll
            for (int p = 0; p < 5; ++p) {
                f32x4 vvn = *(const f32x4*)&smem[vrow + (nh * 5 + p) * 16 + kq * 4];
                float pr = u[p][0] * vvn[0] + u[p][1] * vvn[1]
                         + u[p][2] * vvn[2] + u[p][3] * vvn[3];
                pr += __shfl_xor(pr, 16);
                pr += __shfl_xor(pr, 32);
                cc[p] = pr;
            }
            float s5 = 0.f;
            #pragma unroll
            for (int p = 0; p < 5; ++p) { cc[p] = __expf(cc[p]); s5 += cc[p]; }
            // exchange partial exp-sums between nh halves (parity dbuf,
            // one barrier per j-iter)
            float* ex = exbuf + (jt & 1) * 64;
            if (kq == 0) ex[nh * 32 + bg_l * 16 + bl] = s5;
            __syncthreads();
            const float so = ex[(1 - nh) * 32 + bg_l * 16 + bl];
            const float inv = 1.0f / (s5 + so);
            #pragma unroll
            for (int p = 0; p < 5; ++p) {
                const float cn = cc[p] * inv;
                sac[p][0] = fmaf(cn, u[p][0], sac[p][0]);
                sac[p][1] = fmaf(cn, u[p][1], sac[p][1]);
                sac[p][2] = fmaf(cn, u[p][2], sac[p][2]);
                sac[p][3] = fmaf(cn, u[p][3], sac[p][3]);
            }
        }

        fx = nx;
    }

    // ---- direct store: nh waves own disjoint capsules, no combine ----
    float* pp = part + (size_t)logical * 5120;
    #pragma unroll
    for (int p = 0; p < 5; ++p)
        *(f32x4*)&pp[(bg_l * 16 + bl) * 160 + (nh * 5 + p) * 16 + kq * 4] = sac[p];
}

// Fused reduce (NSLOT slots -> s) + squash + vsum/out. Grid 160 x 1024:
// 16-way k-split; each rq-group covers 36 of the 576 jg-pair super-slots.
__global__ __launch_bounds__(1024) void reduce_kernel(
    const float* __restrict__ part, float* __restrict__ vsum,
    float* __restrict__ out, int iter)
{
    __shared__ float lds[15 * 64];
    const int tid = threadIdx.x;
    const int gi = tid & 63, rq = tid >> 6;       // rq 0..15
    const int g  = blockIdx.x * 64 + gi;          // 0..10239
    const float* p0 = part + g;                   // slot parity encodes bh
    float acc = 0.f;
    for (int k = rq * 36; k < rq * 36 + 36; ++k)  // 16*36 = 576 jg pairs
        acc += p0[(size_t)k * 10240];
    if (rq > 0) lds[(rq - 1) * 64 + gi] = acc;
    __syncthreads();
    if (rq == 0) {
        #pragma unroll
        for (int r = 0; r < 15; ++r) acc += lds[r * 64 + gi];
        float sq = acc * acc;                     // squash over o = bits 0..3
        sq += __shfl_xor(sq, 1);
        sq += __shfl_xor(sq, 2);
        sq += __shfl_xor(sq, 4);
        sq += __shfl_xor(sq, 8);
        float scale = (sq / (1.f + sq)) / sqrtf(sq + 1e-7f);
        float v = scale * acc;
        if (iter == 2)      out[g] = v;
        else if (iter == 0) vsum[g] = v;
        else                vsum[g] += v;
    }
}

extern "C" void kernel_launch(void* const* d_in, const int* in_sizes, int n_in,
                              void* d_out, int out_size, void* d_ws, size_t ws_size,
                              hipStream_t stream) {
    (void)in_sizes; (void)n_in; (void)out_size;
    const float* x = (const float*)d_in[0];   // [64, 6912, 16]
    const float* W = (const float*)d_in[1];   // [10, 6912, 16, 16]
    float* out = (float*)d_out;               // [64, 10, 16]

    const size_t wt_sh = (size_t)IC * NCAP * 256;   // shorts (35.4 MB)
    const size_t xt_sh = (size_t)IC * 4 * 256;      // shorts (14.2 MB)
    const size_t part_f = (size_t)NSLOT * 5120;     // floats (23.6 MB)
    const size_t need_xt = wt_sh * 2 + xt_sh * 2 + part_f * 4 + 10240 * 4;

    int use_xt = (ws_size >= need_xt) ? 1 : 0;
    unsigned short* w_t = (unsigned short*)d_ws;
    unsigned short* x_t = use_xt ? (w_t + wt_sh) : nullptr;
    float* part = (float*)(use_xt ? (void*)(x_t + xt_sh) : (void*)(w_t + wt_sh));
    float* vsum = part + part_f;

    prep_kernel<<<use_xt ? (WBLK + IC / 2) : WBLK, 256, 0, stream>>>(x, W, w_t, x_t, use_xt);
    for (int iter = 0; iter < 3; ++iter) {
        sweep_kernel<<<NSLOT, 256, 0, stream>>>(x, x_t, w_t, vsum, part, iter, use_xt);
        reduce_kernel<<<160, 1024, 0, stream>>>(part, vsum, out, iter);
    }
}